// Round 4
// baseline (18040.326 us; speedup 1.0000x reference)
//
#include <hip/hip_runtime.h>
#include <hip/hip_bf16.h>
#include <stdint.h>

typedef unsigned int uint;
typedef unsigned short ushort;

#define TPB 256

// ---------------- ws layout ----------------
// bf16 weights packed:
//   ws[base + (kb*ROWS + j)*8 + kl] = bf16(W[j][kb*8+kl]); uint4 load -> 8 k-consecutive of row j
#define OFF_A0 0
#define OFF_A1 (768*256)
#define OFF_A2 (2*768*256)
#define OFF_A3 (3*768*256)
#define OFF_A4 (4*768*256)
#define WS_USHORTS (4*768*256 + 320*256)   // 868352
#define WB_BYTES ((size_t)WS_USHORTS * 2)  // 1736704, 16B aligned
// float exchange region: hx[parity2][layer2][b64][256]
#define HX_FLOATS (2*2*64*256)             // 65536
// flags: fl[layer2][b64][q4]
#define FL_UINTS (2*64*4)                  // 512

__device__ __forceinline__ float bflo(uint u){ return __uint_as_float(u << 16); }
__device__ __forceinline__ float bfhi(uint u){ return __uint_as_float(u & 0xffff0000u); }
__device__ __forceinline__ float sigm(float x){ return 1.0f / (1.0f + __expf(-x)); }
__device__ __forceinline__ float tanh_(float x){
    float xc = fminf(fmaxf(x, -15.0f), 15.0f);
    float e  = __expf(2.0f * xc);
    return (e - 1.0f) / (e + 1.0f);
}

// ---------------- prep: transpose+pack+bf16 all weights; zero sync flags ----------------
__global__ void prep_kernel(const float* __restrict__ Wih0, const float* __restrict__ Whh0,
                            const float* __restrict__ Wih1, const float* __restrict__ Whh1,
                            const float* __restrict__ Wint, ushort* __restrict__ ws,
                            uint* __restrict__ fl)
{
    int idx = blockIdx.x * 256 + threadIdx.x;
    if (idx < FL_UINTS) fl[idx] = 0u;          // zero ALL 512 flags (global idx)
    if (idx >= WS_USHORTS) return;
    const float* src; int rows; int base; int p;
    if (idx < 4*768*256) {
        int m = idx / (768*256); p = idx % (768*256);
        src  = (m==0) ? Wih0 : (m==1) ? Whh0 : (m==2) ? Wih1 : Whh1;
        rows = 768; base = m * (768*256);
    } else {
        p = idx - 4*768*256; src = Wint; rows = 320; base = 4*768*256;
    }
    int kb  = p / (rows*8);
    int rem = p - kb*(rows*8);
    int j   = rem >> 3;
    int kl  = rem & 7;
    int k   = kb*8 + kl;
    __hip_bfloat16 h = __float2bfloat16(src[j*256 + k]);
    ws[base + p] = *reinterpret_cast<ushort*>(&h);
}

// single mat-vec row (bf16 packed weights, fp32 LDS input), 2 partial accumulators
template<int ROWS>
__device__ __forceinline__ float mv_row(const ushort* __restrict__ W, const float* vin,
                                        float acc, int j)
{
    const uint4* P = (const uint4*)W;
    float a0 = acc, a1 = 0.f;
#pragma unroll 4
    for (int kb = 0; kb < 32; ++kb) {
        uint4 w = P[kb*ROWS + j];
        float4 va = *(const float4*)&vin[kb*8];
        float4 vb = *(const float4*)&vin[kb*8 + 4];
        a0 += bflo(w.x)*va.x + bfhi(w.x)*va.y + bflo(w.y)*va.z + bfhi(w.y)*va.w;
        a1 += bflo(w.z)*vb.x + bfhi(w.z)*vb.y + bflo(w.w)*vb.z + bfhi(w.w)*vb.w;
    }
    return a0 + a1;
}

// dual mat-vec row (gi from vin, gh from hin) — 2 independent chains
__device__ __forceinline__ void dual_mv2(const ushort* __restrict__ Wi, const ushort* __restrict__ Wh,
                                         const float* vin, const float* hin,
                                         float bi, float bh, float* oi, float* oh, int j)
{
    const uint4* Pi = (const uint4*)Wi;
    const uint4* Ph = (const uint4*)Wh;
    float ai = bi, ah = bh;
#pragma unroll 4
    for (int kb = 0; kb < 32; ++kb) {
        uint4 wi = Pi[kb*768 + j];
        uint4 wh = Ph[kb*768 + j];
        float4 va = *(const float4*)&vin[kb*8];
        float4 vb = *(const float4*)&vin[kb*8 + 4];
        float4 ha = *(const float4*)&hin[kb*8];
        float4 hb = *(const float4*)&hin[kb*8 + 4];
        ai += bflo(wi.x)*va.x + bfhi(wi.x)*va.y + bflo(wi.y)*va.z + bfhi(wi.y)*va.w
            + bflo(wi.z)*vb.x + bfhi(wi.z)*vb.y + bflo(wi.w)*vb.z + bfhi(wi.w)*vb.w;
        ah += bflo(wh.x)*ha.x + bfhi(wh.x)*ha.y + bflo(wh.y)*ha.z + bfhi(wh.y)*ha.w
            + bflo(wh.z)*hb.x + bfhi(wh.z)*hb.y + bflo(wh.w)*hb.z + bfhi(wh.w)*hb.w;
    }
    *oi = ai; *oh = ah;
}

__device__ __forceinline__ void spin_ge(uint* f, uint v){
    while (__hip_atomic_load(f, __ATOMIC_RELAXED, __HIP_MEMORY_SCOPE_AGENT) < v) {}
}
// coherent (cache-bypassing) float load/store at agent scope — no L2 invalidation needed
__device__ __forceinline__ float coh_ld(float* p){
    return __hip_atomic_load(p, __ATOMIC_RELAXED, __HIP_MEMORY_SCOPE_AGENT);
}
__device__ __forceinline__ void coh_st(float* p, float v){
    __hip_atomic_store(p, v, __ATOMIC_RELAXED, __HIP_MEMORY_SCOPE_AGENT);
}

__global__ __launch_bounds__(TPB) void ebm_main(
    const float* __restrict__ x, const float* __restrict__ h0i,
    const float* __restrict__ b_ih0, const float* __restrict__ b_hh0,
    const float* __restrict__ b_ih1, const float* __restrict__ b_hh1,
    const float* __restrict__ b_int, const float* __restrict__ Wmix,
    const float* __restrict__ bmix,
    const ushort* __restrict__ ws, float* __restrict__ hx, uint* __restrict__ fl,
    float* __restrict__ out)
{
    __shared__ float v[256];             // ctl
    __shared__ float gi[192], gh[192];
    __shared__ float h0s[256], h1s[256]; // full hidden states (local copies)
    __shared__ float lread[128];
    __shared__ float em[64][33], bm[64][33];
    __shared__ float itf[320];
    __shared__ float minv_em[64], minv_bm[64], kinv[8];
    __shared__ float sc[8][64];
    __shared__ float wwv[64], ev[32], emer[32];
    __shared__ float emrd[4][32], bmrd[4][32];
    __shared__ float wmix_s[32][65];

    const int tid = threadIdx.x;
    const int b   = blockIdx.x & 63;   // batch
    const int q   = blockIdx.x >> 6;   // row-quarter 0..3  ({b,b+64,b+128,b+192} -> same XCD heuristic)

    // ---- init state ----
    h0s[tid] = h0i[b*256 + tid];
    h1s[tid] = h0i[(64 + b)*256 + tid];
    for (int i = tid; i < 64*33; i += TPB) { (&em[0][0])[i] = 0.f; (&bm[0][0])[i] = 0.f; }
    if (tid < 128) lread[tid] = 0.f;
    for (int i = tid; i < 32*64; i += TPB) wmix_s[i >> 6][i & 63] = Wmix[i];
    __syncthreads();

    for (int t = 0; t < 512; ++t) {
        const size_t outbase = ((size_t)b*512 + t) * 640;
        const int par = t & 1;
        const uint tv = (uint)(t + 1);

        // ---- ctl = [x_t, l_read] ----
        if (tid < 128) v[tid] = x[((size_t)b*512 + t)*128 + tid];
        else           v[tid] = lread[tid - 128];
        __syncthreads();

        // ---- layer0 dual mat-vec on our 192 gate rows ----
        if (tid < 192) {
            int g = tid >> 6, i = tid & 63;
            int j = g*256 + q*64 + i;
            dual_mv2(ws + OFF_A0, ws + OFF_A1, v, h0s, b_ih0[j], b_hh0[j], &gi[tid], &gh[tid], j);
        }
        __syncthreads();
        if (tid < 64) {
            float r  = sigm(gi[tid]       + gh[tid]);
            float z  = sigm(gi[64 + tid]  + gh[64 + tid]);
            float n  = tanh_(gi[128 + tid] + r * gh[128 + tid]);
            float hn = (1.f - z) * n + z * h0s[q*64 + tid];
            coh_st(&hx[((par*2 + 0)*64 + b)*256 + q*64 + tid], hn);  // write-through to MALL
            out[outbase + q*64 + tid] = hn;
        }
        __syncthreads();   // also protects gh[] reuse below
        if (tid == 0) {
            __builtin_amdgcn_fence(__ATOMIC_RELEASE, "agent");   // drain stores before flag
            __hip_atomic_store(&fl[(0*64 + b)*4 + q], tv, __ATOMIC_RELAXED, __HIP_MEMORY_SCOPE_AGENT);
        }

        // ---- overlap with h0 exchange: gh_L1 (needs only local h1s) + bm row norms ----
        if (tid < 192) {
            int g = tid >> 6, i = tid & 63;
            int j = g*256 + q*64 + i;
            gh[tid] = mv_row<768>(ws + OFF_A3, h1s, b_hh1[j], j);
        } else {
            int n = tid - 192; float s = 0.f;
#pragma unroll
            for (int w2 = 0; w2 < 32; ++w2) { float q2 = bm[n][w2]; s += q2*q2; }
            minv_bm[n] = 1.f / (sqrtf(s) + 1e-8f);
        }

        // ---- wait h0 exchange, read full h0n (coherent loads; no cache invalidation) ----
        if (tid < 4) spin_ge(&fl[(0*64 + b)*4 + tid], tv);
        __syncthreads();
        asm volatile("" ::: "memory");
        h0s[tid] = coh_ld(&hx[((par*2 + 0)*64 + b)*256 + tid]);
        __syncthreads();

        // ---- layer1 gi + combine ----
        if (tid < 192) {
            int g = tid >> 6, i = tid & 63;
            int j = g*256 + q*64 + i;
            gi[tid] = mv_row<768>(ws + OFF_A2, h0s, b_ih1[j], j);
        }
        __syncthreads();
        if (tid < 64) {
            float r  = sigm(gi[tid]       + gh[tid]);
            float z  = sigm(gi[64 + tid]  + gh[64 + tid]);
            float n  = tanh_(gi[128 + tid] + r * gh[128 + tid]);
            float hn = (1.f - z) * n + z * h1s[q*64 + tid];
            coh_st(&hx[((par*2 + 1)*64 + b)*256 + q*64 + tid], hn);
            out[outbase + 256 + q*64 + tid] = hn;
        }
        __syncthreads();
        if (tid == 0) {
            __builtin_amdgcn_fence(__ATOMIC_RELEASE, "agent");
            __hip_atomic_store(&fl[(1*64 + b)*4 + q], tv, __ATOMIC_RELAXED, __HIP_MEMORY_SCOPE_AGENT);
        }
        if (tid < 4) spin_ge(&fl[(1*64 + b)*4 + tid], tv);
        __syncthreads();
        asm volatile("" ::: "memory");
        h1s[tid] = coh_ld(&hx[((par*2 + 1)*64 + b)*256 + tid]);
        __syncthreads();

        // ---- interface (replicated full): itf = clip(relu(W_int @ h1n + b_int)) ----
        {
            float a = mv_row<320>(ws + OFF_A4, h1s, b_int[tid], tid);
            itf[tid] = fminf(fmaxf(a, 0.f), 20.f);
            if (tid < 64) {
                float a2 = mv_row<320>(ws + OFF_A4, h1s, b_int[256 + tid], 256 + tid);
                itf[256 + tid] = fminf(fmaxf(a2, 0.f), 20.f);
            }
        }
        __syncthreads();

        // ---- memory module (replicated; identical arithmetic in all 4 peer blocks) ----
        const int slot = t & 63;
        if (tid < 32) {
            emer[tid] = em[slot][tid];
            em[slot][tid] = itf[256 + tid];
            ev[tid] = sigm(itf[288 + tid]);
        } else if (tid < 40) {
            int r = tid - 32;
            const float* kk = &itf[r*32];
            float s = 0.f;
#pragma unroll
            for (int w2 = 0; w2 < 32; ++w2) { float q2 = kk[w2]; s += q2*q2; }
            kinv[r] = 1.f / (sqrtf(s) + 1e-8f);
        }
        __syncthreads();
        if (tid < 64) {
            float s = 0.f;
#pragma unroll
            for (int w2 = 0; w2 < 32; ++w2) { float q2 = em[tid][w2]; s += q2*q2; }
            minv_em[tid] = 1.f / (sqrtf(s) + 1e-8f);
        }
        __syncthreads();
#pragma unroll
        for (int it = 0; it < 2; ++it) {
            int idx = tid + it*256;
            int mm = idx >> 8, r = (idx >> 6) & 3, n = idx & 63;
            const float* kk = &itf[mm*128 + r*32];
            const float (*M)[33] = mm ? bm : em;
            float d = 0.f;
#pragma unroll
            for (int w2 = 0; w2 < 32; ++w2) d += kk[w2] * M[n][w2];
            float val = d * kinv[mm*4 + r] * (mm ? minv_bm[n] : minv_em[n]);
            if (!mm) val *= (1.f/0.3f);
            sc[mm*4 + r][n] = val;
        }
        __syncthreads();
        {
            int wave = tid >> 6, lane = tid & 63;
#pragma unroll
            for (int rr = wave; rr < 8; rr += 4) {
                float val = sc[rr][lane];
                float m = val;
                for (int o = 32; o > 0; o >>= 1) m = fmaxf(m, __shfl_xor(m, o));
                float e = __expf(val - m);
                float s = e;
                for (int o = 32; o > 0; o >>= 1) s += __shfl_xor(s, o);
                sc[rr][lane] = e / s;
            }
        }
        __syncthreads();
        if (tid < 64) wwv[tid] = 0.25f * (sc[4][tid] + sc[5][tid] + sc[6][tid] + sc[7][tid]);
        {
            int mm = tid >> 7, r = (tid >> 5) & 3, w2 = tid & 31;
            const float (*M)[33] = mm ? bm : em;
            const float* wr = sc[mm*4 + r];
            float a = 0.f;
#pragma unroll 8
            for (int n = 0; n < 64; ++n) a += wr[n] * M[n][w2];
            if (mm) bmrd[r][w2] = a; else emrd[r][w2] = a;
        }
        __syncthreads();
        if (tid < 128) {
            int r = tid >> 5, w2 = tid & 31;
            float a = bmix[w2];
#pragma unroll
            for (int c = 0; c < 32; ++c) a += wmix_s[w2][c]      * emrd[r][c];
#pragma unroll
            for (int c = 0; c < 32; ++c) a += wmix_s[w2][32 + c] * bmrd[r][c];
            float g  = sigm(a);
            float rd = g * emrd[r][w2] + (1.f - g) * bmrd[r][w2];
            lread[tid] = rd;
            if (q == 0) out[outbase + 512 + tid] = rd;
        } else {
            for (int i2 = tid - 128; i2 < 2048; i2 += TPB - 128) {
                int n = i2 >> 5, w2 = i2 & 31;
                bm[n][w2] = bm[n][w2] * (1.f - wwv[n]*ev[w2]) + wwv[n]*emer[w2];
            }
        }
        __syncthreads();
    }
}

extern "C" void kernel_launch(void* const* d_in, const int* in_sizes, int n_in,
                              void* d_out, int out_size, void* d_ws, size_t ws_size,
                              hipStream_t stream)
{
    const float* x    = (const float*)d_in[0];
    const float* h0   = (const float*)d_in[1];
    const float* Wih0 = (const float*)d_in[2];
    const float* Whh0 = (const float*)d_in[3];
    const float* bih0 = (const float*)d_in[4];
    const float* bhh0 = (const float*)d_in[5];
    const float* Wih1 = (const float*)d_in[6];
    const float* Whh1 = (const float*)d_in[7];
    const float* bih1 = (const float*)d_in[8];
    const float* bhh1 = (const float*)d_in[9];
    const float* Wint = (const float*)d_in[10];
    const float* bint = (const float*)d_in[11];
    const float* Wmix = (const float*)d_in[12];
    const float* bmix = (const float*)d_in[13];

    ushort* ws = (ushort*)d_ws;
    float*  hx = (float*)((char*)d_ws + WB_BYTES);
    uint*   fl = (uint*)((char*)d_ws + WB_BYTES + (size_t)HX_FLOATS*4);
    float*  out = (float*)d_out;

    const size_t need = WB_BYTES + (size_t)HX_FLOATS*4 + (size_t)FL_UINTS*4;
    if (ws_size < need) return;

    prep_kernel<<<(WS_USHORTS + 255)/256, 256, 0, stream>>>(Wih0, Whh0, Wih1, Whh1, Wint, ws, fl);
    ebm_main<<<256, TPB, 0, stream>>>(x, h0, bih0, bhh0, bih1, bhh1, bint, Wmix, bmix,
                                      ws, hx, fl, out);
}

// Round 6
// 12472.725 us; speedup vs baseline: 1.4464x; 1.4464x over previous
//
#include <hip/hip_runtime.h>
#include <hip/hip_bf16.h>
#include <hip/hip_fp16.h>
#include <stdint.h>

typedef unsigned int uint;
typedef unsigned short ushort;

#define TPB 768

// ---------------- ws layout (ushorts = f16) ----------------
// pack layout for a [ROWS][256] row-major source:
//   ws[base + (kb*ROWS + j)*8 + kl] = f16( W[j][kb*8+kl] )
// -> one uint4 load at (kb*ROWS + j) yields 8 consecutive-k weights of row j.
#define OFF_A0 0
#define OFF_A1 (768*256)
#define OFF_A2 (2*768*256)
#define OFF_A3 (3*768*256)
#define OFF_A4 (4*768*256)
#define WS_USHORTS (4*768*256 + 320*256)   // 868352

__device__ __forceinline__ __half2 h2cast(uint u){
    union { uint u; __half2 h; } c; c.u = u; return c.h;
}
__device__ __forceinline__ float sigm(float x){ return 1.0f / (1.0f + __expf(-x)); }
__device__ __forceinline__ float tanh_(float x){
    float xc = fminf(fmaxf(x, -15.0f), 15.0f);
    float e  = __expf(2.0f * xc);
    return (e - 1.0f) / (e + 1.0f);
}

// ---------------- prep: transpose+pack+f16 all weights ----------------
__global__ void prep_kernel(const float* __restrict__ Wih0, const float* __restrict__ Whh0,
                            const float* __restrict__ Wih1, const float* __restrict__ Whh1,
                            const float* __restrict__ Wint, ushort* __restrict__ ws)
{
    int idx = blockIdx.x * 256 + threadIdx.x;
    if (idx >= WS_USHORTS) return;
    const float* src; int rows; int base; int p;
    if (idx < 4*768*256) {
        int m = idx / (768*256); p = idx % (768*256);
        src  = (m==0) ? Wih0 : (m==1) ? Whh0 : (m==2) ? Wih1 : Whh1;
        rows = 768; base = m * (768*256);
    } else {
        p = idx - 4*768*256; src = Wint; rows = 320; base = 4*768*256;
    }
    int kb  = p / (rows*8);
    int rem = p - kb*(rows*8);
    int j   = rem >> 3;
    int kl  = rem & 7;
    int k   = kb*8 + kl;
    __half h = __float2half_rn(src[j*256 + k]);
    ws[base + p] = *reinterpret_cast<ushort*>(&h);
}

// two rows (j0, j1) of the SAME matrix against one shared input vector.
// f16 weights; each `acc += __low2float(h)*x` statement contracts to v_fma_mix_f32.
template<int ROWS>
__device__ __forceinline__ void mv2_row(const ushort* __restrict__ W, const float* vin,
                                        float b0, float b1, float* o0, float* o1,
                                        int j0, int j1)
{
    const uint4* P = (const uint4*)W;
    float p0a = b0, p0b = 0.f, p1a = b1, p1b = 0.f;
#pragma unroll 4
    for (int kb = 0; kb < 32; ++kb) {
        uint4 w0 = P[kb*ROWS + j0];
        uint4 w1 = P[kb*ROWS + j1];
        float4 va = *(const float4*)&vin[kb*8];
        float4 vb = *(const float4*)&vin[kb*8 + 4];
        __half2 h;
        h = h2cast(w0.x); p0a += __low2float(h)*va.x; p0a += __high2float(h)*va.y;
        h = h2cast(w0.y); p0a += __low2float(h)*va.z; p0a += __high2float(h)*va.w;
        h = h2cast(w0.z); p0b += __low2float(h)*vb.x; p0b += __high2float(h)*vb.y;
        h = h2cast(w0.w); p0b += __low2float(h)*vb.z; p0b += __high2float(h)*vb.w;
        h = h2cast(w1.x); p1a += __low2float(h)*va.x; p1a += __high2float(h)*va.y;
        h = h2cast(w1.y); p1a += __low2float(h)*va.z; p1a += __high2float(h)*va.w;
        h = h2cast(w1.z); p1b += __low2float(h)*vb.x; p1b += __high2float(h)*vb.y;
        h = h2cast(w1.w); p1b += __low2float(h)*vb.z; p1b += __high2float(h)*vb.w;
    }
    *o0 = p0a + p0b;
    *o1 = p1a + p1b;
}

__global__ __launch_bounds__(TPB) void ebm_main(
    const float* __restrict__ x, const float* __restrict__ h0i,
    const float* __restrict__ b_ih0, const float* __restrict__ b_hh0,
    const float* __restrict__ b_ih1, const float* __restrict__ b_hh1,
    const float* __restrict__ b_int, const float* __restrict__ Wmix,
    const float* __restrict__ bmix,
    const ushort* __restrict__ ws, float* __restrict__ out)
{
    __shared__ float v[256];            // ctl input vector
    __shared__ float gi[768], gh[768];
    __shared__ float h0s[256], h1s[256];
    __shared__ float lread[128];
    __shared__ float em[64][33], bm[64][33];   // +1 pad: kills stride-32 conflicts
    __shared__ float itf[320];
    __shared__ float minv_em[64], minv_bm[64], kinv[8];
    __shared__ float sc[8][64];
    __shared__ float wwv[64], ev[32], emer[32];
    __shared__ float emrd[4][32], bmrd[4][32];
    __shared__ float wmix_s[32][65];

    const int tid = threadIdx.x;
    const int b   = blockIdx.x;

    // ---- init state ----
    if (tid < 256) { h0s[tid] = h0i[b*256 + tid]; h1s[tid] = h0i[(64 + b)*256 + tid]; }
    for (int i = tid; i < 64*33; i += TPB) { (&em[0][0])[i] = 0.f; (&bm[0][0])[i] = 0.f; }
    if (tid < 128) lread[tid] = 0.f;
    for (int i = tid; i < 32*64; i += TPB) { wmix_s[i >> 6][i & 63] = Wmix[i]; }
    __syncthreads();

    for (int t = 0; t < 512; ++t) {
        const size_t outbase = ((size_t)b*512 + t) * 640;

        // ---- build ctl = [x_t, l_read] ----
        if (tid < 128)      v[tid] = x[((size_t)b*512 + t)*128 + tid];
        else if (tid < 256) v[tid] = lread[tid - 128];
        __syncthreads();

        // ---- GRU layer 0: gi (Wih0@ctl) on threads 0-383, gh (Whh0@h0) on 384-767 ----
        if (tid < 384) {
            mv2_row<768>(ws + OFF_A0, v, b_ih0[tid], b_ih0[tid + 384],
                         &gi[tid], &gi[tid + 384], tid, tid + 384);
        } else {
            int i = tid - 384;
            mv2_row<768>(ws + OFF_A1, h0s, b_hh0[i], b_hh0[i + 384],
                         &gh[i], &gh[i + 384], i, i + 384);
        }
        __syncthreads();
        if (tid < 256) {
            float r  = sigm(gi[tid]       + gh[tid]);
            float z  = sigm(gi[256 + tid] + gh[256 + tid]);
            float n  = tanh_(gi[512 + tid] + r * gh[512 + tid]);
            float hn = (1.f - z) * n + z * h0s[tid];
            h0s[tid] = hn;
            out[outbase + tid] = hn;
        }
        __syncthreads();

        // ---- GRU layer 1 ----
        if (tid < 384) {
            mv2_row<768>(ws + OFF_A2, h0s, b_ih1[tid], b_ih1[tid + 384],
                         &gi[tid], &gi[tid + 384], tid, tid + 384);
        } else {
            int i = tid - 384;
            mv2_row<768>(ws + OFF_A3, h1s, b_hh1[i], b_hh1[i + 384],
                         &gh[i], &gh[i + 384], i, i + 384);
        }
        __syncthreads();
        if (tid < 256) {
            float r  = sigm(gi[tid]       + gh[tid]);
            float z  = sigm(gi[256 + tid] + gh[256 + tid]);
            float n  = tanh_(gi[512 + tid] + r * gh[512 + tid]);
            float hn = (1.f - z) * n + z * h1s[tid];
            h1s[tid] = hn;
            out[outbase + 256 + tid] = hn;
        }
        __syncthreads();

        // ---- interface: itf = clip(relu(W_int @ h1n + b_int), -20, 20) ----
        if (tid < 160) {
            float a0, a1;
            mv2_row<320>(ws + OFF_A4, h1s, b_int[tid], b_int[tid + 160],
                         &a0, &a1, tid, tid + 160);
            itf[tid]       = fminf(fmaxf(a0, 0.f), 20.f);
            itf[tid + 160] = fminf(fmaxf(a1, 0.f), 20.f);
        }
        __syncthreads();

        // ---- memory ops: save erased slot, write m_t, key norms ----
        const int slot = t & 63;
        if (tid < 32) {
            emer[tid] = em[slot][tid];          // old em slot (em_erased)
            em[slot][tid] = itf[256 + tid];     // em_new: write m_t
            ev[tid] = sigm(itf[288 + tid]);     // e = sigmoid(e_t)
        }
        if (tid >= 32 && tid < 40) {            // key inverse norms (4 em keys, 4 bm keys)
            int r = tid - 32;
            const float* kk = &itf[r*32];
            float s = 0.f;
#pragma unroll
            for (int w2 = 0; w2 < 32; ++w2) { float q = kk[w2]; s += q*q; }
            kinv[r] = 1.f / (sqrtf(s) + 1e-8f);
        }
        __syncthreads();

        // ---- memory row inverse norms (em AFTER slot write; bm OLD) ----
        if (tid < 64) {
            float s = 0.f;
#pragma unroll
            for (int w2 = 0; w2 < 32; ++w2) { float q = em[tid][w2]; s += q*q; }
            minv_em[tid] = 1.f / (sqrtf(s) + 1e-8f);
        } else if (tid < 128) {
            int n = tid - 64; float s = 0.f;
#pragma unroll
            for (int w2 = 0; w2 < 32; ++w2) { float q = bm[n][w2]; s += q*q; }
            minv_bm[n] = 1.f / (sqrtf(s) + 1e-8f);
        }
        __syncthreads();

        // ---- cosine scores (512 dots of length 32) ----
        if (tid < 512) {
            int mm = tid >> 8, r = (tid >> 6) & 3, n = tid & 63;
            const float* kk = &itf[mm*128 + r*32];
            const float (*M)[33] = mm ? bm : em;
            float d = 0.f;
#pragma unroll
            for (int w2 = 0; w2 < 32; ++w2) d += kk[w2] * M[n][w2];
            float val = d * kinv[mm*4 + r] * (mm ? minv_bm[n] : minv_em[n]);
            if (!mm) val *= (1.f/0.3f);         // tau for em path
            sc[mm*4 + r][n] = val;
        }
        __syncthreads();

        // ---- softmax over 64 slots: one wave per (mm,r) row ----
        {
            int wave = tid >> 6, lane = tid & 63;
            if (wave < 8) {
                float val = sc[wave][lane];
                float m = val;
                for (int o = 32; o > 0; o >>= 1) m = fmaxf(m, __shfl_xor(m, o));
                float e = __expf(val - m);
                float s = e;
                for (int o = 32; o > 0; o >>= 1) s += __shfl_xor(s, o);
                sc[wave][lane] = e / s;
            }
        }
        __syncthreads();

        // ---- ww (mean of bm weights over r) + weighted reads ----
        if (tid < 64) wwv[tid] = 0.25f * (sc[4][tid] + sc[5][tid] + sc[6][tid] + sc[7][tid]);
        if (tid < 256) {
            int mm = tid >> 7, r = (tid >> 5) & 3, w2 = tid & 31;
            const float (*M)[33] = mm ? bm : em;
            const float* wr = sc[mm*4 + r];
            float a = 0.f;
#pragma unroll 8
            for (int n = 0; n < 64; ++n) a += wr[n] * M[n][w2];
            if (mm) bmrd[r][w2] = a; else emrd[r][w2] = a;
        }
        __syncthreads();

        // ---- mix gate + l_read (threads 0..127) ; bm update (threads 128..767) ----
        if (tid < 128) {
            int r = tid >> 5, w2 = tid & 31;
            float a = bmix[w2];
#pragma unroll
            for (int c = 0; c < 32; ++c) a += wmix_s[w2][c]      * emrd[r][c];
#pragma unroll
            for (int c = 0; c < 32; ++c) a += wmix_s[w2][32 + c] * bmrd[r][c];
            float g  = sigm(a);
            float rd = g * emrd[r][w2] + (1.f - g) * bmrd[r][w2];
            lread[tid] = rd;
            out[outbase + 512 + tid] = rd;
        } else {
            for (int i2 = tid - 128; i2 < 2048; i2 += TPB - 128) {
                int n = i2 >> 5, w2 = i2 & 31;
                bm[n][w2] = bm[n][w2] * (1.f - wwv[n]*ev[w2]) + wwv[n]*emer[w2];
            }
        }
        __syncthreads();
    }
}

extern "C" void kernel_launch(void* const* d_in, const int* in_sizes, int n_in,
                              void* d_out, int out_size, void* d_ws, size_t ws_size,
                              hipStream_t stream)
{
    const float* x    = (const float*)d_in[0];
    const float* h0   = (const float*)d_in[1];
    const float* Wih0 = (const float*)d_in[2];
    const float* Whh0 = (const float*)d_in[3];
    const float* bih0 = (const float*)d_in[4];
    const float* bhh0 = (const float*)d_in[5];
    const float* Wih1 = (const float*)d_in[6];
    const float* Whh1 = (const float*)d_in[7];
    const float* bih1 = (const float*)d_in[8];
    const float* bhh1 = (const float*)d_in[9];
    const float* Wint = (const float*)d_in[10];
    const float* bint = (const float*)d_in[11];
    const float* Wmix = (const float*)d_in[12];
    const float* bmix = (const float*)d_in[13];
    ushort* ws = (ushort*)d_ws;
    float*  out = (float*)d_out;

    if (ws_size < (size_t)WS_USHORTS * sizeof(ushort)) return;  // need ~1.7 MB scratch

    prep_kernel<<<(WS_USHORTS + 255)/256, 256, 0, stream>>>(Wih0, Whh0, Wih1, Whh1, Wint, ws);
    ebm_main<<<64, TPB, 0, stream>>>(x, h0, bih0, bhh0, bih1, bhh1, bint, Wmix, bmix, ws, out);
}